// Round 17
// baseline (728.393 us; speedup 1.0000x reference)
//
#include <hip/hip_runtime.h>

// Vanilla tanh RNN. B=64, T=2048, I=64, H=128, fp32.
//   xw[b,t,h] = sum_i x[b,t,i]*W[h,i] + b_ih[h] + b_hh[h]
//   h_t = tanh(xw_t + h_{t-1} @ U^T);  outputs: ys [B,T,H], h_last [B,H]
//
// R22. Post-mortem R21 (scan 588us, VGPR STUCK at 40): the empty-asm
// cluster forced 17 co-live values and the allocator paid for them by
// EVICTING u (again) instead of growing past 40. 5th allocator fight
// (R6/R8/R16/R19/R21) — hints lose. Structural fix, two coupled moves:
//  (1) Loads become ASM-DEFINED: 4x ds_read_b128 as real inline asm
//      ("=&v" v4f outputs, one s_waitcnt lgkmcnt(0) inside). Results
//      can't be rematerialized from LDS -> no reload escape hatch;
//      reads issue back-to-back; ONE latency instead of 4 serial.
//      (volatile-asm order vs volatile barrier asm = correct; LDS addr
//      = low 32 bits of generic pointer, SHARED aperture low half = 0.)
//  (2) Register headroom: DROP p0/p1 chunk prefetch (8 persistent
//      VGPRs); stage xbuf synchronously in Phase A (~20us cost).
//      Phase-B live set: u32+hv16+xv1+acc8+addr6 ~= 63 <= 64 = the
//      allocator's demonstrated budget -> u stays resident WITH the
//      cluster. Same cluster in gemm (w32+hv16+acc8 ~= 60).
// Rest identical to R17 (proven 557us): lgkm-only barriers, 20j skew,
// 3-stage DPP butterfly {0xB1,0x4E,0x141}, xv pipeline, obuf staging.

#define RNN_B 64
#define RNN_T 2048
#define RNN_I 64
#define RNN_H 128
#define CH    32            // timesteps per staged chunk
#define NCH   (RNN_T / CH)  // 64 chunks

typedef float v4f __attribute__((ext_vector_type(4)));

__device__ __forceinline__ float fast_tanh(float x) {
  // tanh(x) = 1 - 2/(e^{2x}+1);  e^{2x} = exp2(x * 2*log2(e))
  float e = __builtin_amdgcn_exp2f(x * 2.885390081777927f);
  return 1.0f - 2.0f * __builtin_amdgcn_rcpf(e + 1.0f);
}

template <int CTRL>
__device__ __forceinline__ float dpp_add(float s) {
  int o = __builtin_amdgcn_mov_dpp(__float_as_int(s), CTRL, 0xF, 0xF, true);
  return s + __int_as_float(o);
}

__device__ __forceinline__ void fma4v(float4& a, const float4 u, const v4f h) {
  a.x = fmaf(u.x, h.x, a.x);
  a.y = fmaf(u.y, h.y, a.y);
  a.z = fmaf(u.z, h.z, a.z);
  a.w = fmaf(u.w, h.w, a.w);
}

__device__ __forceinline__ float hsum(const float4 a) {
  return (a.x + a.y) + (a.z + a.w);
}

// LDS byte offset from a generic pointer into __shared__ (SHARED aperture
// has zero low 32 bits, so truncation yields the LDS offset).
__device__ __forceinline__ unsigned lds_off(const void* p) {
  return (unsigned)(unsigned long long)p;
}

// Clustered 4x ds_read_b128 from one base: issued back-to-back, one wait,
// results asm-defined (cannot be rematerialized -> stay in VGPRs).
__device__ __forceinline__ void ds_read4(unsigned base, v4f& r0, v4f& r1,
                                         v4f& r2, v4f& r3) {
  asm volatile(
      "ds_read_b128 %0, %4\n\t"
      "ds_read_b128 %1, %4 offset:16\n\t"
      "ds_read_b128 %2, %4 offset:32\n\t"
      "ds_read_b128 %3, %4 offset:48\n\t"
      "s_waitcnt lgkmcnt(0)"
      : "=&v"(r0), "=&v"(r1), "=&v"(r2), "=&v"(r3)
      : "v"(base));
}

// Workgroup barrier WITHOUT the vmcnt(0) drain __syncthreads implies.
// Steps touch only LDS; outstanding global flush stores may float across.
__device__ __forceinline__ void barrier_lgkm() {
  asm volatile("s_waitcnt lgkmcnt(0)\n\ts_barrier" ::: "memory");
}

// ---------------------------------------------------------------------------
// Kernel 1: xw = x @ W^T + (b_ih + b_hh).  M=B*T=131072, N=128, K=64.
// 2048 blocks x 256 threads, 64 x-rows/block, 2 blocks/CU.
// thread -> (g=tid>>2: rows 2g,2g+1; q=tid&3: cols [16q,16q+16)):
// 8 float4 of W in regs. Per row: ds_read4 cluster (one LDS latency).
// Quad butterfly (xor1+xor2); lanes q<2 store row 2g+q (coalesced).
// ---------------------------------------------------------------------------
__global__ __launch_bounds__(256, 2) void rnn_xw_gemm(
    const float* __restrict__ x, const float* __restrict__ W,
    const float* __restrict__ b_ih, const float* __restrict__ b_hh,
    float* __restrict__ xw) {
  const int tid = threadIdx.x;
  const int g   = tid >> 2;   // 0..63 : rows 2g, 2g+1
  const int q   = tid & 3;    // col slice [16q, 16q+16)

  // W tile: rows 2g,2g+1, cols [16q,16q+16) -> 8 float4 (32 VGPRs)
  float4 w[2][4];
#pragma unroll
  for (int r = 0; r < 2; ++r) {
    const float4* Wr = (const float4*)(W + (2 * g + r) * RNN_I + 16 * q);
#pragma unroll
    for (int m = 0; m < 4; ++m) w[r][m] = Wr[m];
  }
  const int row_own = 2 * g + (q & 1);
  const float bias  = b_ih[row_own] + b_hh[row_own];

  // Stage 64 rows of x (64x64 fp32 = 16 KB) into LDS, coalesced.
  __shared__ __align__(16) float4 xs[64 * 16];
  const long rbase = (long)blockIdx.x * 64;
  const float4* xg = (const float4*)(x + rbase * RNN_I);
#pragma unroll
  for (int jj = 0; jj < 4; ++jj) xs[tid + 256 * jj] = xg[tid + 256 * jj];
  __syncthreads();

#pragma unroll 2
  for (int r = 0; r < 64; ++r) {
    v4f hv0, hv1, hv2, hv3;
    ds_read4(lds_off(xs + r * 16 + q * 4), hv0, hv1, hv2, hv3);
    float4 a0 = {0, 0, 0, 0}, a1 = {0, 0, 0, 0};
    fma4v(a0, w[0][0], hv0); fma4v(a0, w[0][1], hv1);
    fma4v(a0, w[0][2], hv2); fma4v(a0, w[0][3], hv3);
    fma4v(a1, w[1][0], hv0); fma4v(a1, w[1][1], hv1);
    fma4v(a1, w[1][2], hv2); fma4v(a1, w[1][3], hv3);
    float s0 = hsum(a0), s1 = hsum(a1);
    s0 = dpp_add<0xB1>(s0); s0 = dpp_add<0x4E>(s0);
    s1 = dpp_add<0xB1>(s1); s1 = dpp_add<0x4E>(s1);
    const float own = (q & 1) ? s1 : s0;
    if (q < 2)
      xw[(rbase + r) * RNN_H + row_own] = own + bias;
  }
}

// ---------------------------------------------------------------------------
// Kernel 2: sequential scan. 1 block/batch, 512 threads (8 waves, 2/SIMD).
// R17 core + asm-clustered reads + synchronous Phase A staging (frees the
// 8 prefetch VGPRs so the cluster fits without evicting u).
// thread(g=tid>>3: rows 2g,2g+1; j=tid&7: cols [16j,16j+16)):
// 8 float4 of U in regs. ds_read4 per step (20j skew, conflict-free) ->
// 1 LDS latency on the chain. 3-stage DPP butterfly; j<2 writes next-h,
// j==4,5 writes obuf. lgkm-only barriers.
// ---------------------------------------------------------------------------
__global__ __launch_bounds__(512, 2) void rnn_scan(
    const float* xw,            // aliases `out` — no __restrict__
    float* out, float* __restrict__ hlast,
    const float* __restrict__ h0, const float* __restrict__ U) {
  const int b     = blockIdx.x;
  const int tid   = threadIdx.x;  // 0..511
  const int g     = tid >> 3;     // 0..63 : rows 2g, 2g+1
  const int j     = tid & 7;      // k-slice [16j, 16j+16)
  const int r_own = 2 * g + (j & 1);

  __shared__ __align__(16) float hbuf0[8 * 20];     // skewed h state
  __shared__ __align__(16) float hbuf1[8 * 20];
  __shared__ __align__(16) float xbuf[CH * RNN_H];  // 16 KB
  __shared__ __align__(16) float obuf[CH * RNN_H];  // 16 KB

  // U tile: rows 2g,2g+1, cols [16j,16j+16) -> 8 float4 (32 VGPRs)
  float4 u[2][4];
#pragma unroll
  for (int r = 0; r < 2; ++r) {
    const float4* Ur = (const float4*)(U + (2 * g + r) * RNN_H + 16 * j);
#pragma unroll
    for (int m = 0; m < 4; ++m) u[r][m] = Ur[m];
  }

  if (tid < RNN_H)
    hbuf0[(tid >> 4) * 20 + (tid & 15)] = h0[b * RNN_H + tid];

  const int hoff = (r_own >> 4) * 20 + (r_own & 15);  // skewed write slot
  const unsigned hb0 = lds_off(hbuf0 + 20 * j);       // cluster base, ping 0
  const unsigned hb1 = lds_off(hbuf1 + 20 * j);       // cluster base, ping 1
  const long base   = (long)b * RNN_T * RNN_H;
  const float4* xw4 = (const float4*)(xw + base);
  float4* out4      = (float4*)(out + base);
  float4* xb4       = (float4*)xbuf;
  const float4* ob4 = (const float4*)obuf;

  float xv_cur;  // xw value for the CURRENT step, read one step ahead

  auto step = [&](unsigned hb, float* dst, int tc) {
    v4f hv0, hv1, hv2, hv3;
    ds_read4(hb, hv0, hv1, hv2, hv3);   // asm-defined: co-live by force
    float xv_next = xbuf[((tc + 1) & (CH - 1)) * RNN_H + r_own];
    float4 a0 = {0, 0, 0, 0}, a1 = {0, 0, 0, 0};
    fma4v(a0, u[0][0], hv0); fma4v(a0, u[0][1], hv1);
    fma4v(a0, u[0][2], hv2); fma4v(a0, u[0][3], hv3);
    fma4v(a1, u[1][0], hv0); fma4v(a1, u[1][1], hv1);
    fma4v(a1, u[1][2], hv2); fma4v(a1, u[1][3], hv3);
    float s0 = hsum(a0), s1 = hsum(a1);
    s0 = dpp_add<0xB1>(s0); s0 = dpp_add<0x4E>(s0); s0 = dpp_add<0x141>(s0);
    s1 = dpp_add<0xB1>(s1); s1 = dpp_add<0x4E>(s1); s1 = dpp_add<0x141>(s1);
    const float own = (j & 1) ? s1 : s0;
    const float val = fast_tanh(own + xv_cur);
    if (j < 2) {
      dst[hoff] = val;                      // ds_write: next h state
    } else if ((j & 6) == 4) {              // j == 4,5
      obuf[tc * RNN_H + r_own] = val;       // ds_write: staged output
    }
    barrier_lgkm();                         // no vmcnt drain (proven R17)
    xv_cur = xv_next;
  };

  for (int c = 0; c < NCH; ++c) {
    // Phase A: stage chunk c synchronously (transient regs only — the 8
    // freed prefetch VGPRs are what lets the step cluster keep u);
    // flush chunk c-1's outputs (stores float across lgkm barriers).
    const float4* nx = xw4 + (long)c * 1024;
    float4 t0 = nx[tid], t1 = nx[tid + 512];
    if (c > 0) {
      out4[(long)(c - 1) * 1024 + tid]       = ob4[tid];
      out4[(long)(c - 1) * 1024 + tid + 512] = ob4[tid + 512];
    }
    xb4[tid] = t0; xb4[tid + 512] = t1;
    barrier_lgkm();

    // Phase B: 32 steps, LDS-only traffic, compile-time h ping-pong.
    xv_cur = xbuf[r_own];  // tc = 0 of this chunk
    for (int tc = 0; tc < CH; tc += 2) {
      step(hb0, hbuf1, tc);
      step(hb1, hbuf0, tc + 1);
    }
  }

  // Final chunk flush + h_last (last step's barrier makes data visible)
  out4[(long)(NCH - 1) * 1024 + tid]       = ob4[tid];
  out4[(long)(NCH - 1) * 1024 + tid + 512] = ob4[tid + 512];
  if (tid < RNN_H)
    hlast[b * RNN_H + tid] = hbuf0[(tid >> 4) * 20 + (tid & 15)];
}

extern "C" void kernel_launch(void* const* d_in, const int* in_sizes, int n_in,
                              void* d_out, int out_size, void* d_ws, size_t ws_size,
                              hipStream_t stream) {
  const float* x    = (const float*)d_in[0];
  const float* h0   = (const float*)d_in[1];
  const float* W    = (const float*)d_in[2];
  const float* U    = (const float*)d_in[3];
  const float* b_ih = (const float*)d_in[4];
  const float* b_hh = (const float*)d_in[5];

  float* out   = (float*)d_out;                           // [B,T,H]
  float* hlast = out + (long)RNN_B * RNN_T * RNN_H;       // [B,H]

  // Stage 1: xw into the output region (read-before-write in scan, per chunk)
  rnn_xw_gemm<<<(RNN_B * RNN_T) / 64, 256, 0, stream>>>(x, W, b_ih, b_hh, out);
  // Stage 2: sequential recurrence, one block per batch element
  rnn_scan<<<RNN_B, 512, 0, stream>>>(out, out, hlast, h0, U);
}

// Round 18
// 716.036 us; speedup vs baseline: 1.0173x; 1.0173x over previous
//
#include <hip/hip_runtime.h>

// Vanilla tanh RNN. B=64, T=2048, I=64, H=128, fp32.
//   xw[b,t,h] = sum_i x[b,t,i]*W[h,i] + b_ih[h] + b_hh[h]
//   h_t = tanh(xw_t + h_{t-1} @ U^T);  outputs: ys [B,T,H], h_last [B,H]
//
// R23. Post-mortem R22 (scan 627us, VGPR=36): asm-forced hv co-liveness
// was paid for by evicting u AGAIN. Six rounds of VGPR data (60/64/36/
// 40/48/36) reveal the law: the GCN scheduler CLAMPS register pressure
// to the 64-VGPR tier because LDS=34KB permits 4 blocks/CU = 8 waves/
// SIMD, and it optimizes for that occupancy. But the scan runs 64
// blocks on 256 CUs — every CU hosts exactly ONE block (2 waves/SIMD)
// regardless. The frugality buys nothing and costs serial latency.
// Fix: tell the compiler the truth, two independent levers:
//  (1) __attribute__((amdgpu_waves_per_eu(1,2))): occupancy target <=2
//      waves/EU -> register ceiling ~256.
//  (2) CH 32->64: LDS 66.8KB -> max 2 blocks/CU by LDS -> even the
//      LDS-derived target is 4 waves/SIMD = 128-VGPR tier. (Free: only
//      1 block/CU exists anyway. Bonus: chunk boundaries 64 -> 32.)
// With headroom: keep R22's asm ds_read4 cluster (4 reads, 1 wait,
// results asm-pinned) AND restore R17's p-prefetch (16 VGPRs). Phase-B
// live set ~82 <= 128 -> u resident WITH the cluster, finally.
// GO/NO-GO: scan VGPR >= 64. Gemm = R22 verbatim (2048 blocks, real
// occupancy matters there — do not restrict its waves).

#define RNN_B 64
#define RNN_T 2048
#define RNN_I 64
#define RNN_H 128
#define CH    64            // timesteps per staged chunk (LDS lever!)
#define NCH   (RNN_T / CH)  // 32 chunks

typedef float v4f __attribute__((ext_vector_type(4)));

__device__ __forceinline__ float fast_tanh(float x) {
  // tanh(x) = 1 - 2/(e^{2x}+1);  e^{2x} = exp2(x * 2*log2(e))
  float e = __builtin_amdgcn_exp2f(x * 2.885390081777927f);
  return 1.0f - 2.0f * __builtin_amdgcn_rcpf(e + 1.0f);
}

template <int CTRL>
__device__ __forceinline__ float dpp_add(float s) {
  int o = __builtin_amdgcn_mov_dpp(__float_as_int(s), CTRL, 0xF, 0xF, true);
  return s + __int_as_float(o);
}

__device__ __forceinline__ void fma4v(float4& a, const float4 u, const v4f h) {
  a.x = fmaf(u.x, h.x, a.x);
  a.y = fmaf(u.y, h.y, a.y);
  a.z = fmaf(u.z, h.z, a.z);
  a.w = fmaf(u.w, h.w, a.w);
}

__device__ __forceinline__ float hsum(const float4 a) {
  return (a.x + a.y) + (a.z + a.w);
}

// LDS byte offset from a generic pointer into __shared__ (SHARED aperture
// has zero low 32 bits, so truncation yields the LDS offset).
__device__ __forceinline__ unsigned lds_off(const void* p) {
  return (unsigned)(unsigned long long)p;
}

// Clustered 4x ds_read_b128 from one base: issued back-to-back, one wait,
// results asm-defined (cannot be rematerialized -> stay in VGPRs).
__device__ __forceinline__ void ds_read4(unsigned base, v4f& r0, v4f& r1,
                                         v4f& r2, v4f& r3) {
  asm volatile(
      "ds_read_b128 %0, %4\n\t"
      "ds_read_b128 %1, %4 offset:16\n\t"
      "ds_read_b128 %2, %4 offset:32\n\t"
      "ds_read_b128 %3, %4 offset:48\n\t"
      "s_waitcnt lgkmcnt(0)"
      : "=&v"(r0), "=&v"(r1), "=&v"(r2), "=&v"(r3)
      : "v"(base));
}

// Workgroup barrier WITHOUT the vmcnt(0) drain __syncthreads implies.
// Steps touch only LDS; outstanding global prefetch/flush may float across.
__device__ __forceinline__ void barrier_lgkm() {
  asm volatile("s_waitcnt lgkmcnt(0)\n\ts_barrier" ::: "memory");
}

// ---------------------------------------------------------------------------
// Kernel 1: xw = x @ W^T + (b_ih + b_hh).  M=B*T=131072, N=128, K=64.
// 2048 blocks x 256 threads, 64 x-rows/block, 2 blocks/CU. (R22 verbatim.)
// ---------------------------------------------------------------------------
__global__ __launch_bounds__(256, 2) void rnn_xw_gemm(
    const float* __restrict__ x, const float* __restrict__ W,
    const float* __restrict__ b_ih, const float* __restrict__ b_hh,
    float* __restrict__ xw) {
  const int tid = threadIdx.x;
  const int g   = tid >> 2;   // 0..63 : rows 2g, 2g+1
  const int q   = tid & 3;    // col slice [16q, 16q+16)

  // W tile: rows 2g,2g+1, cols [16q,16q+16) -> 8 float4 (32 VGPRs)
  float4 w[2][4];
#pragma unroll
  for (int r = 0; r < 2; ++r) {
    const float4* Wr = (const float4*)(W + (2 * g + r) * RNN_I + 16 * q);
#pragma unroll
    for (int m = 0; m < 4; ++m) w[r][m] = Wr[m];
  }
  const int row_own = 2 * g + (q & 1);
  const float bias  = b_ih[row_own] + b_hh[row_own];

  // Stage 64 rows of x (64x64 fp32 = 16 KB) into LDS, coalesced.
  __shared__ __align__(16) float4 xs[64 * 16];
  const long rbase = (long)blockIdx.x * 64;
  const float4* xg = (const float4*)(x + rbase * RNN_I);
#pragma unroll
  for (int jj = 0; jj < 4; ++jj) xs[tid + 256 * jj] = xg[tid + 256 * jj];
  __syncthreads();

#pragma unroll 2
  for (int r = 0; r < 64; ++r) {
    v4f hv0, hv1, hv2, hv3;
    ds_read4(lds_off(xs + r * 16 + q * 4), hv0, hv1, hv2, hv3);
    float4 a0 = {0, 0, 0, 0}, a1 = {0, 0, 0, 0};
    fma4v(a0, w[0][0], hv0); fma4v(a0, w[0][1], hv1);
    fma4v(a0, w[0][2], hv2); fma4v(a0, w[0][3], hv3);
    fma4v(a1, w[1][0], hv0); fma4v(a1, w[1][1], hv1);
    fma4v(a1, w[1][2], hv2); fma4v(a1, w[1][3], hv3);
    float s0 = hsum(a0), s1 = hsum(a1);
    s0 = dpp_add<0xB1>(s0); s0 = dpp_add<0x4E>(s0);
    s1 = dpp_add<0xB1>(s1); s1 = dpp_add<0x4E>(s1);
    const float own = (q & 1) ? s1 : s0;
    if (q < 2)
      xw[(rbase + r) * RNN_H + row_own] = own + bias;
  }
}

// ---------------------------------------------------------------------------
// Kernel 2: sequential scan. 64 blocks (1/batch) x 512 threads — at most
// ONE block per CU, so occupancy target is declared as 1-2 waves/EU to
// unlock the register file (R23 levers: attribute + 66.8KB LDS).
// thread(g=tid>>3: rows 2g,2g+1; j=tid&7: cols [16j,16j+16)):
// 8 float4 of U in regs; ds_read4 cluster per step (20j skew,
// conflict-free); 3-stage DPP butterfly {0xB1,0x4E,0x141}; j<2 writes
// next-h, j==4,5 writes obuf; p-prefetch one chunk ahead; lgkm barriers.
// ---------------------------------------------------------------------------
__global__ __launch_bounds__(512)
__attribute__((amdgpu_waves_per_eu(1, 2)))
void rnn_scan(
    const float* xw,            // aliases `out` — no __restrict__
    float* out, float* __restrict__ hlast,
    const float* __restrict__ h0, const float* __restrict__ U) {
  const int b     = blockIdx.x;
  const int tid   = threadIdx.x;  // 0..511
  const int g     = tid >> 3;     // 0..63 : rows 2g, 2g+1
  const int j     = tid & 7;      // k-slice [16j, 16j+16)
  const int r_own = 2 * g + (j & 1);

  __shared__ __align__(16) float hbuf0[8 * 20];     // skewed h state
  __shared__ __align__(16) float hbuf1[8 * 20];
  __shared__ __align__(16) float xbuf[CH * RNN_H];  // 32 KB (CH=64)
  __shared__ __align__(16) float obuf[CH * RNN_H];  // 32 KB

  // U tile: rows 2g,2g+1, cols [16j,16j+16) -> 8 float4 (32 VGPRs)
  float4 u[2][4];
#pragma unroll
  for (int r = 0; r < 2; ++r) {
    const float4* Ur = (const float4*)(U + (2 * g + r) * RNN_H + 16 * j);
#pragma unroll
    for (int m = 0; m < 4; ++m) u[r][m] = Ur[m];
  }

  if (tid < RNN_H)
    hbuf0[(tid >> 4) * 20 + (tid & 15)] = h0[b * RNN_H + tid];

  const int hoff = (r_own >> 4) * 20 + (r_own & 15);  // skewed write slot
  const unsigned hb0 = lds_off(hbuf0 + 20 * j);       // cluster base, ping 0
  const unsigned hb1 = lds_off(hbuf1 + 20 * j);       // cluster base, ping 1
  const long base   = (long)b * RNN_T * RNN_H;
  const float4* xw4 = (const float4*)(xw + base);
  float4* out4      = (float4*)(out + base);
  float4* xb4       = (float4*)xbuf;
  const float4* ob4 = (const float4*)obuf;

  // Prologue: prefetch chunk 0 into regs (4 float4/thread, CH=64).
  float4 p0 = xw4[tid],        p1 = xw4[tid + 512],
         p2 = xw4[tid + 1024], p3 = xw4[tid + 1536];

  float xv_cur;  // xw value for the CURRENT step, read one step ahead

  auto step = [&](unsigned hb, float* dst, int tc) {
    v4f hv0, hv1, hv2, hv3;
    ds_read4(hb, hv0, hv1, hv2, hv3);   // 4 reads, 1 wait, co-live by force
    float xv_next = xbuf[((tc + 1) & (CH - 1)) * RNN_H + r_own];
    float4 a0 = {0, 0, 0, 0}, a1 = {0, 0, 0, 0};
    fma4v(a0, u[0][0], hv0); fma4v(a0, u[0][1], hv1);
    fma4v(a0, u[0][2], hv2); fma4v(a0, u[0][3], hv3);
    fma4v(a1, u[1][0], hv0); fma4v(a1, u[1][1], hv1);
    fma4v(a1, u[1][2], hv2); fma4v(a1, u[1][3], hv3);
    float s0 = hsum(a0), s1 = hsum(a1);
    s0 = dpp_add<0xB1>(s0); s0 = dpp_add<0x4E>(s0); s0 = dpp_add<0x141>(s0);
    s1 = dpp_add<0xB1>(s1); s1 = dpp_add<0x4E>(s1); s1 = dpp_add<0x141>(s1);
    const float own = (j & 1) ? s1 : s0;
    const float val = fast_tanh(own + xv_cur);
    if (j < 2) {
      dst[hoff] = val;                      // ds_write: next h state
    } else if ((j & 6) == 4) {              // j == 4,5
      obuf[tc * RNN_H + r_own] = val;       // ds_write: staged output
    }
    barrier_lgkm();                         // no vmcnt drain (proven R17)
    xv_cur = xv_next;
  };

  for (int c = 0; c < NCH; ++c) {
    // Phase A: commit prefetched chunk c; issue prefetch of c+1 (floats
    // across the lgkm-only barriers); flush chunk c-1's outputs.
    xb4[tid] = p0; xb4[tid + 512] = p1;
    xb4[tid + 1024] = p2; xb4[tid + 1536] = p3;
    if (c + 1 < NCH) {
      const float4* nx = xw4 + (long)(c + 1) * 2048;
      p0 = nx[tid];        p1 = nx[tid + 512];
      p2 = nx[tid + 1024]; p3 = nx[tid + 1536];
    }
    if (c > 0) {
      float4* od = out4 + (long)(c - 1) * 2048;
      od[tid]        = ob4[tid];        od[tid + 512]  = ob4[tid + 512];
      od[tid + 1024] = ob4[tid + 1024]; od[tid + 1536] = ob4[tid + 1536];
    }
    barrier_lgkm();

    // Phase B: 64 steps, LDS-only traffic, compile-time h ping-pong.
    xv_cur = xbuf[r_own];  // tc = 0 of this chunk
    for (int tc = 0; tc < CH; tc += 2) {
      step(hb0, hbuf1, tc);
      step(hb1, hbuf0, tc + 1);
    }
  }

  // Final chunk flush + h_last (last step's barrier makes data visible)
  {
    float4* od = out4 + (long)(NCH - 1) * 2048;
    od[tid]        = ob4[tid];        od[tid + 512]  = ob4[tid + 512];
    od[tid + 1024] = ob4[tid + 1024]; od[tid + 1536] = ob4[tid + 1536];
  }
  if (tid < RNN_H)
    hlast[b * RNN_H + tid] = hbuf0[(tid >> 4) * 20 + (tid & 15)];
}

extern "C" void kernel_launch(void* const* d_in, const int* in_sizes, int n_in,
                              void* d_out, int out_size, void* d_ws, size_t ws_size,
                              hipStream_t stream) {
  const float* x    = (const float*)d_in[0];
  const float* h0   = (const float*)d_in[1];
  const float* W    = (const float*)d_in[2];
  const float* U    = (const float*)d_in[3];
  const float* b_ih = (const float*)d_in[4];
  const float* b_hh = (const float*)d_in[5];

  float* out   = (float*)d_out;                           // [B,T,H]
  float* hlast = out + (long)RNN_B * RNN_T * RNN_H;       // [B,H]

  // Stage 1: xw into the output region (read-before-write in scan, per chunk)
  rnn_xw_gemm<<<(RNN_B * RNN_T) / 64, 256, 0, stream>>>(x, W, b_ih, b_hh, out);
  // Stage 2: sequential recurrence, one block per batch element
  rnn_scan<<<RNN_B, 512, 0, stream>>>(out, out, hlast, h0, U);
}